// Round 2
// baseline (11962.601 us; speedup 1.0000x reference)
//
#include <hip/hip_runtime.h>
#include <hip/hip_bf16.h>
#include <cstdint>
#include <cstddef>

// BiLSTM tagger, f32 end-to-end.
// embed -> [GEMM pre -> 4-block LSTM scan] x2 -> 4 MLP GEMMs -> bilinear (2 GEMMs).
// Scan: 4 blocks (2 dirs x 2 parts). Each block keeps 400 rows of Whh (200 f32/thread)
// in VGPRs (__launch_bounds__(512,2) -> 256-VGPR cap), owns a 100-elem h-slice, and
// exchanges it with its single partner through L2 (agent atomics + epoch flags).
// Local-half FMA overlaps the partner's release latency.

#define TSEQ 512
#define HDIR 200
#define INSZ 400
#define G4   800

// ---------------- embedding ----------------
__global__ void k_embed(const float* __restrict__ we, const float* __restrict__ pe,
                        const int* __restrict__ wi, const int* __restrict__ pi,
                        float* __restrict__ x) {
  int t = blockIdx.x;
  int w = wi[t], p = pi[t];
  const float* wrow = we + (size_t)w * 300;
  const float* prow = pe + (size_t)p * 100;
  for (int j = threadIdx.x; j < INSZ; j += blockDim.x)
    x[(size_t)t * INSZ + j] = (j < 300) ? wrow[j] : prow[j - 300];
}

__global__ void k_add(const float* __restrict__ a, const float* __restrict__ b,
                      float* __restrict__ o, int n) {
  int i = blockIdx.x * blockDim.x + threadIdx.x;
  if (i < n) o[i] = a[i] + b[i];
}

// ---------------- GEMM: C[n][m] = act(A[n][k] * B[m][k]^T + bias) ----------------
__global__ __launch_bounds__(256) void k_gemm_bt(
    const float* __restrict__ A, const float* __restrict__ B,
    const float* __restrict__ bias, float* __restrict__ C,
    int n, int m, int k, int bias_mode, int do_relu)
{
  __shared__ float As[16][68];
  __shared__ float Bs[16][68];
  const int tid = threadIdx.x;
  const int tx = tid & 15, ty = tid >> 4;
  const int row0 = blockIdx.y << 6, col0 = blockIdx.x << 6;
  const int lr = tid >> 2;          // 0..63
  const int kq = (tid & 3) << 2;    // 0,4,8,12
  float acc[4][4] = {};

  for (int ks = 0; ks < k; ks += 16) {
    float4 a4 = *(const float4*)(A + (size_t)(row0 + lr) * k + ks + kq);
    float4 b4 = make_float4(0.f, 0.f, 0.f, 0.f);
    if (col0 + lr < m)
      b4 = *(const float4*)(B + (size_t)(col0 + lr) * k + ks + kq);
    As[kq + 0][lr] = a4.x; As[kq + 1][lr] = a4.y; As[kq + 2][lr] = a4.z; As[kq + 3][lr] = a4.w;
    Bs[kq + 0][lr] = b4.x; Bs[kq + 1][lr] = b4.y; Bs[kq + 2][lr] = b4.z; Bs[kq + 3][lr] = b4.w;
    __syncthreads();
#pragma unroll
    for (int kk = 0; kk < 16; ++kk) {
      const float4 av = *(const float4*)&As[kk][ty << 2];
      const float4 bv = *(const float4*)&Bs[kk][tx << 2];
      const float a_[4] = {av.x, av.y, av.z, av.w};
      const float b_[4] = {bv.x, bv.y, bv.z, bv.w};
#pragma unroll
      for (int i = 0; i < 4; ++i)
#pragma unroll
        for (int j = 0; j < 4; ++j)
          acc[i][j] += a_[i] * b_[j];
    }
    __syncthreads();
  }

#pragma unroll
  for (int i = 0; i < 4; ++i) {
    const int r = row0 + (ty << 2) + i;
#pragma unroll
    for (int j = 0; j < 4; ++j) {
      const int c = col0 + (tx << 2) + j;
      if (c < m) {
        float v = acc[i][j];
        if (bias_mode == 1) v += bias[c];
        else if (bias_mode == 2) v += bias[0];
        if (do_relu) v = fmaxf(v, 0.f);
        C[(size_t)r * m + c] = v;
      }
    }
  }
}

// ---------------- LSTM scan ----------------
// grid = 4 blocks: dir = bid>>1, part p = bid&1. 512 threads/block.
// Thread tid<400: full Whh row grow = g*200 + p*100 + q (g=tid/100, q=tid%100),
// 50 float4 weights in VGPRs. Block owns h slice [p*100, p*100+100).
__global__ __launch_bounds__(512, 2) void k_scan(
    const float* __restrict__ Whh,   // [2][2][800][200]
    const float* __restrict__ pre,   // [512][1600]
    float* __restrict__ hs,          // [512][400] (concat fwd|bwd)
    float* hbuf,                     // [2 parity][2 dir][200]
    int* epochs,                     // [2 layer][2 dir][2 part] (zeroed)
    int layer)
{
  const int bid = blockIdx.x;
  const int dir = bid >> 1;
  const int p = bid & 1;
  const int tid = threadIdx.x;
  const bool act = tid < 400;
  const int g = tid / 100;           // 0..3 for act threads
  const int q = tid - g * 100;
  const int grow = act ? (g * HDIR + p * 100 + q) : 0;
  const int own_base = p * 100;
  const int rem_base = 100 - own_base;

  __shared__ float h_lds[HDIR];      // full h_t
  __shared__ float g_lds[400];       // gate pre-activations [g*100+q]

  float4 w[50];
  {
    const float* wrow = Whh + ((size_t)(layer * 2 + dir) * G4 + grow) * HDIR;
#pragma unroll
    for (int i = 0; i < 50; ++i) w[i] = *(const float4*)(wrow + i * 4);
  }

  for (int i = tid; i < HDIR; i += 512) h_lds[i] = 0.f;
  float c_state = 0.f;               // valid for tid < 100
  int* ep_base = epochs + layer * 8 + dir * 2;
  int* ep_mine = ep_base + p;
  int* ep_part = ep_base + (1 - p);
  __syncthreads();

  for (int t = 0; t < TSEQ; ++t) {
    const int inrow = dir ? (TSEQ - 1 - t) : t;

    // issue pre load early (latency hides under FMA)
    const float preval = pre[(size_t)inrow * 1600 + dir * G4 + grow];

    // local-half FMA: h_lds own half is valid (written last iter, barrier'd)
    float4 acc = make_float4(0.f, 0.f, 0.f, 0.f);
    {
      const float* hb = h_lds + own_base;
      const int wb0 = p * 25;
#pragma unroll
      for (int i = 0; i < 25; ++i) {
        const float4 hv = *(const float4*)(hb + i * 4);
        const float4 wv = w[wb0 + i];
        acc.x += wv.x * hv.x; acc.y += wv.y * hv.y;
        acc.z += wv.z * hv.z; acc.w += wv.w * hv.w;
      }
    }

    if (t > 0) {
      if (tid < 128) {   // waves 0-1 poll (they contain the gather threads)
        while (__hip_atomic_load(ep_part, __ATOMIC_ACQUIRE,
                                 __HIP_MEMORY_SCOPE_AGENT) < t) {}
      }
      if (tid < 100) {   // gather partner slice for h_t
        const float v = __hip_atomic_load(
            &hbuf[(size_t)(t & 1) * 400 + dir * 200 + rem_base + tid],
            __ATOMIC_RELAXED, __HIP_MEMORY_SCOPE_AGENT);
        h_lds[rem_base + tid] = v;
      }
    }
    __syncthreads();

    // remote-half FMA + gate assembly
    {
      const float* hr = h_lds + rem_base;
      const int wb1 = 25 - p * 25;
#pragma unroll
      for (int i = 0; i < 25; ++i) {
        const float4 hv = *(const float4*)(hr + i * 4);
        const float4 wv = w[wb1 + i];
        acc.x += wv.x * hv.x; acc.y += wv.y * hv.y;
        acc.z += wv.z * hv.z; acc.w += wv.w * hv.w;
      }
    }
    if (act) g_lds[tid] = acc.x + acc.y + acc.z + acc.w + preval;
    __syncthreads();

    if (tid < 100) {
      const float gi = g_lds[tid];
      const float gf = g_lds[100 + tid];
      const float gg = g_lds[200 + tid];
      const float go = g_lds[300 + tid];
      const float si = 1.f / (1.f + __expf(-gi));
      const float sf = 1.f / (1.f + __expf(-gf));
      const float so = 1.f / (1.f + __expf(-go));
      const float tg = 2.f / (1.f + __expf(-2.f * gg)) - 1.f;
      c_state = sf * c_state + si * tg;
      const float tc = 2.f / (1.f + __expf(-2.f * c_state)) - 1.f;
      const float hv = so * tc;
      h_lds[own_base + tid] = hv;
      hs[(size_t)inrow * INSZ + dir * HDIR + own_base + tid] = hv;
      if (t != TSEQ - 1)
        __hip_atomic_store(&hbuf[(size_t)((t + 1) & 1) * 400 + dir * 200 + own_base + tid],
                           hv, __ATOMIC_RELAXED, __HIP_MEMORY_SCOPE_AGENT);
    }
    __syncthreads();   // per-wave vmcnt drain: hbuf slice agent-visible

    if (t != TSEQ - 1 && tid == 0)
      __hip_atomic_store(ep_mine, t + 1, __ATOMIC_RELEASE, __HIP_MEMORY_SCOPE_AGENT);
  }
}

// ---------------- host ----------------
extern "C" void kernel_launch(void* const* d_in, const int* in_sizes, int n_in,
                              void* d_out, int out_size, void* d_ws, size_t ws_size,
                              hipStream_t stream)
{
  const float* we   = (const float*)d_in[0];
  const float* pe   = (const float*)d_in[1];
  const float* Wih  = (const float*)d_in[2];
  const float* Whh  = (const float*)d_in[3];
  const float* bih  = (const float*)d_in[4];
  const float* bhh  = (const float*)d_in[5];
  const float* W_h1 = (const float*)d_in[6];
  const float* b_h1 = (const float*)d_in[7];
  const float* W_h2 = (const float*)d_in[8];
  const float* b_h2 = (const float*)d_in[9];
  const float* W_d1 = (const float*)d_in[10];
  const float* b_d1 = (const float*)d_in[11];
  const float* W_d2 = (const float*)d_in[12];
  const float* b_d2 = (const float*)d_in[13];
  const float* W_bi = (const float*)d_in[14];
  const float* b_bi = (const float*)d_in[15];
  const int*   wi   = (const int*)d_in[16];
  const int*   pi   = (const int*)d_in[17];
  float* out = (float*)d_out;

  float* ws = (float*)d_ws;
  float* x0   = ws;                     // 512*400
  float* pre  = ws + 204800;            // 512*1600
  float* h1   = ws + 1024000;           // 512*400
  float* h2   = ws + 1228800;           // 512*400
  float* m1   = ws + 1433600;           // 512*400 scratch
  float* m2   = ws + 1638400;           // 512*400 (head)
  float* m3   = ws + 1843200;           // 512*400 (dep)
  float* bsum = ws + 2048000;           // 3200
  float* hbuf = ws + 2051200;           // 800
  int* epochs = (int*)(ws + 2052224);   // 16 ints

  hipMemsetAsync(epochs, 0, 16 * sizeof(int), stream);
  k_embed<<<TSEQ, 128, 0, stream>>>(we, pe, wi, pi, x0);
  k_add<<<(3200 + 255) / 256, 256, 0, stream>>>(bih, bhh, bsum, 3200);

  // layer 0: pre = x0 @ Wih[0]^T + (bih+bhh)[0]  -> [512][1600] (dir0 | dir1)
  k_gemm_bt<<<dim3(25, 8), 256, 0, stream>>>(x0, Wih, bsum, pre, 512, 1600, 400, 1, 0);
  k_scan<<<4, 512, 0, stream>>>(Whh, pre, h1, hbuf, epochs, 0);

  // layer 1
  k_gemm_bt<<<dim3(25, 8), 256, 0, stream>>>(h1, Wih + 1600 * 400, bsum + 1600, pre, 512, 1600, 400, 1, 0);
  k_scan<<<4, 512, 0, stream>>>(Whh, pre, h2, hbuf, epochs, 1);

  // head = relu(relu(h2 W_h1^T + b_h1) W_h2^T + b_h2)
  k_gemm_bt<<<dim3(7, 8), 256, 0, stream>>>(h2, W_h1, b_h1, m1, 512, 400, 400, 1, 1);
  k_gemm_bt<<<dim3(7, 8), 256, 0, stream>>>(m1, W_h2, b_h2, m2, 512, 400, 400, 1, 1);
  // dep
  k_gemm_bt<<<dim3(7, 8), 256, 0, stream>>>(h2, W_d1, b_d1, m1, 512, 400, 400, 1, 1);
  k_gemm_bt<<<dim3(7, 8), 256, 0, stream>>>(m1, W_d2, b_d2, m3, 512, 400, 400, 1, 1);

  // bilinear: t1[j][d] = sum_e dep[j][e] * W_bi[d][e]
  k_gemm_bt<<<dim3(7, 8), 256, 0, stream>>>(m3, W_bi, nullptr, m1, 512, 400, 400, 0, 0);
  // out[i][j] = sum_d head[i][d] * t1[j][d] + b_bi
  k_gemm_bt<<<dim3(8, 8), 256, 0, stream>>>(m2, m1, b_bi, out, 512, 512, 400, 2, 0);
}

// Round 3
// 4480.352 us; speedup vs baseline: 2.6700x; 2.6700x over previous
//
#include <hip/hip_runtime.h>
#include <hip/hip_bf16.h>
#include <cstdint>
#include <cstddef>

// BiLSTM tagger, f32 end-to-end.
// embed -> [GEMM pre -> 4-block LSTM scan] x2 -> MLP GEMMs (dual) -> bilinear.
// Scan: 4 blocks (2 dirs x 2 parts). Each block keeps 400 rows of Whh in VGPRs
// (50 float4 = 200 VGPRs, __launch_bounds__(512,2) -> 256 cap). Register indices
// are ALL compile-time (own half = w[0..24], remote = w[25..49]; runtime offset
// lives in the load address) -- rule #20. Cross-block h exchange via packed
// (epoch<<32 | value) 8-byte words in L2: reader spins on the data word itself.

#define TSEQ 512
#define HDIR 200
#define INSZ 400
#define G4   800

typedef unsigned long long u64;

// ---------------- embedding ----------------
__global__ void k_embed(const float* __restrict__ we, const float* __restrict__ pe,
                        const int* __restrict__ wi, const int* __restrict__ pi,
                        float* __restrict__ x) {
  int t = blockIdx.x;
  int w = wi[t], p = pi[t];
  const float* wrow = we + (size_t)w * 300;
  const float* prow = pe + (size_t)p * 100;
  for (int j = threadIdx.x; j < INSZ; j += blockDim.x)
    x[(size_t)t * INSZ + j] = (j < 300) ? wrow[j] : prow[j - 300];
}

__global__ void k_add(const float* __restrict__ a, const float* __restrict__ b,
                      float* __restrict__ o, int n) {
  int i = blockIdx.x * blockDim.x + threadIdx.x;
  if (i < n) o[i] = a[i] + b[i];
}

// ---------------- GEMM: C[n][m] = act(A[n][k] * B[m][k]^T + bias) ----------------
__device__ __forceinline__ void gemm_bt_body(
    const float* __restrict__ A, const float* __restrict__ B,
    const float* __restrict__ bias, float* __restrict__ C,
    int m, int k, int bias_mode, int do_relu, int bx, int by)
{
  __shared__ float As[16][68];
  __shared__ float Bs[16][68];
  const int tid = threadIdx.x;
  const int tx = tid & 15, ty = tid >> 4;
  const int row0 = by << 6, col0 = bx << 6;
  const int lr = tid >> 2;
  const int kq = (tid & 3) << 2;
  float acc[4][4] = {};

  for (int ks = 0; ks < k; ks += 16) {
    float4 a4 = *(const float4*)(A + (size_t)(row0 + lr) * k + ks + kq);
    float4 b4 = make_float4(0.f, 0.f, 0.f, 0.f);
    if (col0 + lr < m)
      b4 = *(const float4*)(B + (size_t)(col0 + lr) * k + ks + kq);
    As[kq + 0][lr] = a4.x; As[kq + 1][lr] = a4.y; As[kq + 2][lr] = a4.z; As[kq + 3][lr] = a4.w;
    Bs[kq + 0][lr] = b4.x; Bs[kq + 1][lr] = b4.y; Bs[kq + 2][lr] = b4.z; Bs[kq + 3][lr] = b4.w;
    __syncthreads();
#pragma unroll
    for (int kk = 0; kk < 16; ++kk) {
      const float4 av = *(const float4*)&As[kk][ty << 2];
      const float4 bv = *(const float4*)&Bs[kk][tx << 2];
      const float a_[4] = {av.x, av.y, av.z, av.w};
      const float b_[4] = {bv.x, bv.y, bv.z, bv.w};
#pragma unroll
      for (int i = 0; i < 4; ++i)
#pragma unroll
        for (int j = 0; j < 4; ++j)
          acc[i][j] += a_[i] * b_[j];
    }
    __syncthreads();
  }

#pragma unroll
  for (int i = 0; i < 4; ++i) {
    const int r = row0 + (ty << 2) + i;
#pragma unroll
    for (int j = 0; j < 4; ++j) {
      const int c = col0 + (tx << 2) + j;
      if (c < m) {
        float v = acc[i][j];
        if (bias_mode == 1) v += bias[c];
        else if (bias_mode == 2) v += bias[0];
        if (do_relu) v = fmaxf(v, 0.f);
        C[(size_t)r * m + c] = v;
      }
    }
  }
}

__global__ __launch_bounds__(256) void k_gemm_bt(
    const float* __restrict__ A, const float* __restrict__ B,
    const float* __restrict__ bias, float* __restrict__ C,
    int m, int k, int bias_mode, int do_relu)
{
  gemm_bt_body(A, B, bias, C, m, k, bias_mode, do_relu, blockIdx.x, blockIdx.y);
}

// two independent B/C pairs sharing A (or different A), selected by blockIdx.z
__global__ __launch_bounds__(256) void k_gemm_bt_dual(
    const float* __restrict__ A0, const float* __restrict__ B0,
    const float* __restrict__ bias0, float* __restrict__ C0,
    const float* __restrict__ A1, const float* __restrict__ B1,
    const float* __restrict__ bias1, float* __restrict__ C1,
    int m, int k, int bias_mode, int do_relu)
{
  const float* A = blockIdx.z ? A1 : A0;
  const float* B = blockIdx.z ? B1 : B0;
  const float* bias = blockIdx.z ? bias1 : bias0;
  float* C = blockIdx.z ? C1 : C0;
  gemm_bt_body(A, B, bias, C, m, k, bias_mode, do_relu, blockIdx.x, blockIdx.y);
}

// ---------------- LSTM scan ----------------
// grid = 4 blocks: dir = bid>>1, part p = bid&1. 512 threads/block.
// Thread tid<400: gate row grow = g*200 + p*100 + q. Weights in VGPRs:
// w[0..24] = own-half columns, w[25..49] = remote-half columns.
// hbuf (per layer): u64[2 slot][2 dir][256], word = (epoch<<32)|bits(h).
__global__ __launch_bounds__(512, 2) void k_scan(
    const float* __restrict__ Whh,   // [2][2][800][200]
    const float* __restrict__ pre,   // [512][1600]
    float* __restrict__ hs,          // [512][400] (concat fwd|bwd)
    u64* hbuf,                       // zeroed by host each launch
    int layer)
{
  const int bid = blockIdx.x;
  const int dir = bid >> 1;
  const int p = bid & 1;
  const int tid = threadIdx.x;
  const bool act = tid < 400;
  const int g = tid / 100;
  const int q = tid - g * 100;
  const int grow = act ? (g * HDIR + p * 100 + q) : 0;
  const int own_base = p * 100;
  const int rem_base = 100 - own_base;

  __shared__ float h_lds[HDIR];
  __shared__ float g_lds[400];

  float4 w[50];   // compile-time indices only
  {
    const float* wrow = Whh + ((size_t)(layer * 2 + dir) * G4 + grow) * HDIR;
    const float* wown = wrow + own_base;
    const float* wrem = wrow + rem_base;
#pragma unroll
    for (int i = 0; i < 25; ++i) w[i] = *(const float4*)(wown + i * 4);
#pragma unroll
    for (int i = 0; i < 25; ++i) w[25 + i] = *(const float4*)(wrem + i * 4);
  }

  for (int i = tid; i < HDIR; i += 512) h_lds[i] = 0.f;
  float c_state = 0.f;               // valid for tid < 100
  __syncthreads();

  for (int t = 0; t < TSEQ; ++t) {
    const int inrow = dir ? (TSEQ - 1 - t) : t;

    const float preval = pre[(size_t)inrow * 1600 + dir * G4 + grow];

    // own-half FMA (h_lds own slice valid from prev iteration)
    float4 acc = make_float4(0.f, 0.f, 0.f, 0.f);
    {
      const float* hb = h_lds + own_base;
#pragma unroll
      for (int i = 0; i < 25; ++i) {
        const float4 hv = *(const float4*)(hb + i * 4);
        acc.x += w[i].x * hv.x; acc.y += w[i].y * hv.y;
        acc.z += w[i].z * hv.z; acc.w += w[i].w * hv.w;
      }
    }

    // spin on partner's packed words (tag carries the data)
    if (t > 0 && tid < 100) {
      const u64* src = hbuf + (size_t)(t & 1) * 512 + dir * 256 + rem_base + tid;
      u64 v;
      do {
        v = __hip_atomic_load(src, __ATOMIC_RELAXED, __HIP_MEMORY_SCOPE_AGENT);
      } while ((unsigned)(v >> 32) < (unsigned)t);
      union { unsigned u; float f; } cv; cv.u = (unsigned)v;
      h_lds[rem_base + tid] = cv.f;
    }
    __syncthreads();

    // remote-half FMA + gate assembly
    {
      const float* hr = h_lds + rem_base;
#pragma unroll
      for (int i = 0; i < 25; ++i) {
        const float4 hv = *(const float4*)(hr + i * 4);
        acc.x += w[25 + i].x * hv.x; acc.y += w[25 + i].y * hv.y;
        acc.z += w[25 + i].z * hv.z; acc.w += w[25 + i].w * hv.w;
      }
    }
    if (act) g_lds[tid] = acc.x + acc.y + acc.z + acc.w + preval;
    __syncthreads();

    if (tid < 100) {
      const float gi = g_lds[tid];
      const float gf = g_lds[100 + tid];
      const float gg = g_lds[200 + tid];
      const float go = g_lds[300 + tid];
      const float si = 1.f / (1.f + __expf(-gi));
      const float sf = 1.f / (1.f + __expf(-gf));
      const float so = 1.f / (1.f + __expf(-go));
      const float tg = 2.f / (1.f + __expf(-2.f * gg)) - 1.f;
      c_state = sf * c_state + si * tg;
      const float tc = 2.f / (1.f + __expf(-2.f * c_state)) - 1.f;
      const float hv = so * tc;
      h_lds[own_base + tid] = hv;
      hs[(size_t)inrow * INSZ + dir * HDIR + own_base + tid] = hv;
      if (t != TSEQ - 1) {
        union { float f; unsigned u; } cv; cv.f = hv;
        const u64 pk = ((u64)(unsigned)(t + 1) << 32) | cv.u;
        __hip_atomic_store(hbuf + (size_t)((t + 1) & 1) * 512 + dir * 256 + own_base + tid,
                           pk, __ATOMIC_RELAXED, __HIP_MEMORY_SCOPE_AGENT);
      }
    }
    __syncthreads();   // h_lds own slice visible block-wide for next iter
  }
}

// ---------------- host ----------------
extern "C" void kernel_launch(void* const* d_in, const int* in_sizes, int n_in,
                              void* d_out, int out_size, void* d_ws, size_t ws_size,
                              hipStream_t stream)
{
  const float* we   = (const float*)d_in[0];
  const float* pe   = (const float*)d_in[1];
  const float* Wih  = (const float*)d_in[2];
  const float* Whh  = (const float*)d_in[3];
  const float* bih  = (const float*)d_in[4];
  const float* bhh  = (const float*)d_in[5];
  const float* W_h1 = (const float*)d_in[6];
  const float* b_h1 = (const float*)d_in[7];
  const float* W_h2 = (const float*)d_in[8];
  const float* b_h2 = (const float*)d_in[9];
  const float* W_d1 = (const float*)d_in[10];
  const float* b_d1 = (const float*)d_in[11];
  const float* W_d2 = (const float*)d_in[12];
  const float* b_d2 = (const float*)d_in[13];
  const float* W_bi = (const float*)d_in[14];
  const float* b_bi = (const float*)d_in[15];
  const int*   wi   = (const int*)d_in[16];
  const int*   pi   = (const int*)d_in[17];
  float* out = (float*)d_out;

  float* ws = (float*)d_ws;
  float* x0   = ws;                     // 512*400
  float* pre  = ws + 204800;            // 512*1600
  float* h1   = ws + 1024000;           // 512*400
  float* h2   = ws + 1228800;           // 512*400
  float* m1h  = ws + 1433600;           // 512*400
  float* m1d  = ws + 1638400;           // 512*400
  float* m2   = ws + 1843200;           // 512*400 (head)
  float* m3   = ws + 2048000;           // 512*400 (dep)
  float* t1   = ws + 2252800;           // 512*400
  float* bsum = ws + 2457600;           // 3200
  u64* hbuf0  = (u64*)(ws + 2461696);   // 1024 u64 (8 KB), layer 0
  u64* hbuf1  = hbuf0 + 1024;           // layer 1

  hipMemsetAsync(hbuf0, 0, 2 * 1024 * sizeof(u64), stream);
  k_embed<<<TSEQ, 128, 0, stream>>>(we, pe, wi, pi, x0);
  k_add<<<(3200 + 255) / 256, 256, 0, stream>>>(bih, bhh, bsum, 3200);

  // layer 0
  k_gemm_bt<<<dim3(25, 8), 256, 0, stream>>>(x0, Wih, bsum, pre, 1600, 400, 1, 0);
  k_scan<<<4, 512, 0, stream>>>(Whh, pre, h1, hbuf0, 0);
  // layer 1
  k_gemm_bt<<<dim3(25, 8), 256, 0, stream>>>(h1, Wih + 1600 * 400, bsum + 1600, pre, 1600, 400, 1, 0);
  k_scan<<<4, 512, 0, stream>>>(Whh, pre, h2, hbuf1, 1);

  // head/dep stage 1 (dual), stage 2 (dual)
  k_gemm_bt_dual<<<dim3(7, 8, 2), 256, 0, stream>>>(h2, W_h1, b_h1, m1h,
                                                    h2, W_d1, b_d1, m1d, 400, 400, 1, 1);
  k_gemm_bt_dual<<<dim3(7, 8, 2), 256, 0, stream>>>(m1h, W_h2, b_h2, m2,
                                                    m1d, W_d2, b_d2, m3, 400, 400, 1, 1);

  // bilinear: t1[j][d] = sum_e dep[j][e] W_bi[d][e]; out[i][j] = head_i . t1_j + b
  k_gemm_bt<<<dim3(7, 8), 256, 0, stream>>>(m3, W_bi, nullptr, t1, 400, 400, 0, 0);
  k_gemm_bt<<<dim3(8, 8), 256, 0, stream>>>(m2, t1, b_bi, out, 512, 400, 2, 0);
}

// Round 4
// 2543.367 us; speedup vs baseline: 4.7035x; 1.7616x over previous
//
#include <hip/hip_runtime.h>
#include <hip/hip_bf16.h>
#include <cstdint>
#include <cstddef>

// BiLSTM tagger, f32 end-to-end.
// embed -> [GEMM pre -> 4-block LSTM scan] x2 -> MLP GEMMs (dual) -> bilinear.
// Scan: 4 blocks (2 dirs x 2 parts), 512 thr. Each block keeps 400 rows of Whh in
// VGPRs (50 float4 = 200 VGPRs). __launch_bounds__(512,1): 8 waves/CU -> 2/SIMD
// -> 256-VGPR cap (512,2 was read as 2 blocks/CU -> 128 cap -> spill, r3).
// Register indices all compile-time (rule #20). Cross-block h exchange via packed
// (epoch<<32 | value) u64 words in L2; reader spins on the data word itself.

#define TSEQ 512
#define HDIR 200
#define INSZ 400
#define G4   800

typedef unsigned long long u64;

// ---------------- embedding ----------------
__global__ void k_embed(const float* __restrict__ we, const float* __restrict__ pe,
                        const int* __restrict__ wi, const int* __restrict__ pi,
                        float* __restrict__ x) {
  int t = blockIdx.x;
  int w = wi[t], p = pi[t];
  const float* wrow = we + (size_t)w * 300;
  const float* prow = pe + (size_t)p * 100;
  for (int j = threadIdx.x; j < INSZ; j += blockDim.x)
    x[(size_t)t * INSZ + j] = (j < 300) ? wrow[j] : prow[j - 300];
}

__global__ void k_add(const float* __restrict__ a, const float* __restrict__ b,
                      float* __restrict__ o, int n) {
  int i = blockIdx.x * blockDim.x + threadIdx.x;
  if (i < n) o[i] = a[i] + b[i];
}

// ---------------- GEMM: C[n][m] = act(A[n][k] * B[m][k]^T + bias) ----------------
__device__ __forceinline__ void gemm_bt_body(
    const float* __restrict__ A, const float* __restrict__ B,
    const float* __restrict__ bias, float* __restrict__ C,
    int m, int k, int bias_mode, int do_relu, int bx, int by)
{
  __shared__ float As[16][68];
  __shared__ float Bs[16][68];
  const int tid = threadIdx.x;
  const int tx = tid & 15, ty = tid >> 4;
  const int row0 = by << 6, col0 = bx << 6;
  const int lr = tid >> 2;
  const int kq = (tid & 3) << 2;
  float acc[4][4] = {};

  for (int ks = 0; ks < k; ks += 16) {
    float4 a4 = *(const float4*)(A + (size_t)(row0 + lr) * k + ks + kq);
    float4 b4 = make_float4(0.f, 0.f, 0.f, 0.f);
    if (col0 + lr < m)
      b4 = *(const float4*)(B + (size_t)(col0 + lr) * k + ks + kq);
    As[kq + 0][lr] = a4.x; As[kq + 1][lr] = a4.y; As[kq + 2][lr] = a4.z; As[kq + 3][lr] = a4.w;
    Bs[kq + 0][lr] = b4.x; Bs[kq + 1][lr] = b4.y; Bs[kq + 2][lr] = b4.z; Bs[kq + 3][lr] = b4.w;
    __syncthreads();
#pragma unroll
    for (int kk = 0; kk < 16; ++kk) {
      const float4 av = *(const float4*)&As[kk][ty << 2];
      const float4 bv = *(const float4*)&Bs[kk][tx << 2];
      const float a_[4] = {av.x, av.y, av.z, av.w};
      const float b_[4] = {bv.x, bv.y, bv.z, bv.w};
#pragma unroll
      for (int i = 0; i < 4; ++i)
#pragma unroll
        for (int j = 0; j < 4; ++j)
          acc[i][j] += a_[i] * b_[j];
    }
    __syncthreads();
  }

#pragma unroll
  for (int i = 0; i < 4; ++i) {
    const int r = row0 + (ty << 2) + i;
#pragma unroll
    for (int j = 0; j < 4; ++j) {
      const int c = col0 + (tx << 2) + j;
      if (c < m) {
        float v = acc[i][j];
        if (bias_mode == 1) v += bias[c];
        else if (bias_mode == 2) v += bias[0];
        if (do_relu) v = fmaxf(v, 0.f);
        C[(size_t)r * m + c] = v;
      }
    }
  }
}

__global__ __launch_bounds__(256) void k_gemm_bt(
    const float* __restrict__ A, const float* __restrict__ B,
    const float* __restrict__ bias, float* __restrict__ C,
    int m, int k, int bias_mode, int do_relu)
{
  gemm_bt_body(A, B, bias, C, m, k, bias_mode, do_relu, blockIdx.x, blockIdx.y);
}

__global__ __launch_bounds__(256) void k_gemm_bt_dual(
    const float* __restrict__ A0, const float* __restrict__ B0,
    const float* __restrict__ bias0, float* __restrict__ C0,
    const float* __restrict__ A1, const float* __restrict__ B1,
    const float* __restrict__ bias1, float* __restrict__ C1,
    int m, int k, int bias_mode, int do_relu)
{
  const float* A = blockIdx.z ? A1 : A0;
  const float* B = blockIdx.z ? B1 : B0;
  const float* bias = blockIdx.z ? bias1 : bias0;
  float* C = blockIdx.z ? C1 : C0;
  gemm_bt_body(A, B, bias, C, m, k, bias_mode, do_relu, blockIdx.x, blockIdx.y);
}

// ---------------- LSTM scan ----------------
__global__ __launch_bounds__(512, 1) void k_scan(
    const float* __restrict__ Whh,   // [2][2][800][200]
    const float* __restrict__ pre,   // [512][1600]
    float* __restrict__ hs,          // [512][400] (concat fwd|bwd)
    u64* hbuf,                       // zeroed by host each launch
    int layer)
{
  const int bid = blockIdx.x;
  const int dir = bid >> 1;
  const int p = bid & 1;
  const int tid = threadIdx.x;
  const bool act = tid < 400;
  const int g = tid / 100;
  const int q = tid - g * 100;
  const int grow = act ? (g * HDIR + p * 100 + q) : 0;
  const int own_base = p * 100;
  const int rem_base = 100 - own_base;

  __shared__ float h_lds[HDIR];
  __shared__ float g_lds[400];

  float4 w[50];   // compile-time indices only (rule #20)
  {
    const float* wrow = Whh + ((size_t)(layer * 2 + dir) * G4 + grow) * HDIR;
    const float* wown = wrow + own_base;
    const float* wrem = wrow + rem_base;
#pragma unroll
    for (int i = 0; i < 25; ++i) w[i] = *(const float4*)(wown + i * 4);
#pragma unroll
    for (int i = 0; i < 25; ++i) w[25 + i] = *(const float4*)(wrem + i * 4);
  }

  for (int i = tid; i < HDIR; i += 512) h_lds[i] = 0.f;
  float c_state = 0.f;               // valid for tid < 100
  __syncthreads();

  for (int t = 0; t < TSEQ; ++t) {
    const int inrow = dir ? (TSEQ - 1 - t) : t;

    float preval = 0.f;
    float4 acc = make_float4(0.f, 0.f, 0.f, 0.f);
    if (act) {
      preval = pre[(size_t)inrow * 1600 + dir * G4 + grow];
      // own-half FMA (h_lds own slice valid from prev iteration)
      const float* hb = h_lds + own_base;
#pragma unroll
      for (int i = 0; i < 25; ++i) {
        const float4 hv = *(const float4*)(hb + i * 4);
        acc.x += w[i].x * hv.x; acc.y += w[i].y * hv.y;
        acc.z += w[i].z * hv.z; acc.w += w[i].w * hv.w;
      }
    }

    // spin on partner's packed words (tag carries the data)
    if (t > 0 && tid < 100) {
      const u64* src = hbuf + (size_t)(t & 1) * 512 + dir * 256 + rem_base + tid;
      u64 v;
      do {
        v = __hip_atomic_load(src, __ATOMIC_RELAXED, __HIP_MEMORY_SCOPE_AGENT);
      } while ((unsigned)(v >> 32) < (unsigned)t);
      union { unsigned u; float f; } cv; cv.u = (unsigned)v;
      h_lds[rem_base + tid] = cv.f;
    }
    __syncthreads();

    // remote-half FMA + gate assembly
    if (act) {
      const float* hr = h_lds + rem_base;
#pragma unroll
      for (int i = 0; i < 25; ++i) {
        const float4 hv = *(const float4*)(hr + i * 4);
        acc.x += w[25 + i].x * hv.x; acc.y += w[25 + i].y * hv.y;
        acc.z += w[25 + i].z * hv.z; acc.w += w[25 + i].w * hv.w;
      }
      g_lds[tid] = acc.x + acc.y + acc.z + acc.w + preval;
    }
    __syncthreads();

    if (tid < 100) {
      const float gi = g_lds[tid];
      const float gf = g_lds[100 + tid];
      const float gg = g_lds[200 + tid];
      const float go = g_lds[300 + tid];
      const float si = 1.f / (1.f + __expf(-gi));
      const float sf = 1.f / (1.f + __expf(-gf));
      const float so = 1.f / (1.f + __expf(-go));
      const float tg = 2.f / (1.f + __expf(-2.f * gg)) - 1.f;
      c_state = sf * c_state + si * tg;
      const float tc = 2.f / (1.f + __expf(-2.f * c_state)) - 1.f;
      const float hv = so * tc;
      if (t != TSEQ - 1) {             // publish partner word FIRST
        union { float f; unsigned u; } cv; cv.f = hv;
        const u64 pk = ((u64)(unsigned)(t + 1) << 32) | cv.u;
        __hip_atomic_store(hbuf + (size_t)((t + 1) & 1) * 512 + dir * 256 + own_base + tid,
                           pk, __ATOMIC_RELAXED, __HIP_MEMORY_SCOPE_AGENT);
      }
      h_lds[own_base + tid] = hv;
      hs[(size_t)inrow * INSZ + dir * HDIR + own_base + tid] = hv;
    }
    __syncthreads();   // h_lds own slice visible block-wide for next iter
  }
}

// ---------------- host ----------------
extern "C" void kernel_launch(void* const* d_in, const int* in_sizes, int n_in,
                              void* d_out, int out_size, void* d_ws, size_t ws_size,
                              hipStream_t stream)
{
  const float* we   = (const float*)d_in[0];
  const float* pe   = (const float*)d_in[1];
  const float* Wih  = (const float*)d_in[2];
  const float* Whh  = (const float*)d_in[3];
  const float* bih  = (const float*)d_in[4];
  const float* bhh  = (const float*)d_in[5];
  const float* W_h1 = (const float*)d_in[6];
  const float* b_h1 = (const float*)d_in[7];
  const float* W_h2 = (const float*)d_in[8];
  const float* b_h2 = (const float*)d_in[9];
  const float* W_d1 = (const float*)d_in[10];
  const float* b_d1 = (const float*)d_in[11];
  const float* W_d2 = (const float*)d_in[12];
  const float* b_d2 = (const float*)d_in[13];
  const float* W_bi = (const float*)d_in[14];
  const float* b_bi = (const float*)d_in[15];
  const int*   wi   = (const int*)d_in[16];
  const int*   pi   = (const int*)d_in[17];
  float* out = (float*)d_out;

  float* ws = (float*)d_ws;
  float* x0   = ws;                     // 512*400
  float* pre  = ws + 204800;            // 512*1600
  float* h1   = ws + 1024000;           // 512*400
  float* h2   = ws + 1228800;           // 512*400
  float* m1h  = ws + 1433600;           // 512*400
  float* m1d  = ws + 1638400;           // 512*400
  float* m2   = ws + 1843200;           // 512*400 (head)
  float* m3   = ws + 2048000;           // 512*400 (dep)
  float* t1   = ws + 2252800;           // 512*400
  float* bsum = ws + 2457600;           // 3200
  u64* hbuf0  = (u64*)(ws + 2461696);   // 1024 u64, layer 0
  u64* hbuf1  = hbuf0 + 1024;           // layer 1

  hipMemsetAsync(hbuf0, 0, 2 * 1024 * sizeof(u64), stream);
  k_embed<<<TSEQ, 128, 0, stream>>>(we, pe, wi, pi, x0);
  k_add<<<(3200 + 255) / 256, 256, 0, stream>>>(bih, bhh, bsum, 3200);

  // layer 0
  k_gemm_bt<<<dim3(25, 8), 256, 0, stream>>>(x0, Wih, bsum, pre, 1600, 400, 1, 0);
  k_scan<<<4, 512, 0, stream>>>(Whh, pre, h1, hbuf0, 0);
  // layer 1
  k_gemm_bt<<<dim3(25, 8), 256, 0, stream>>>(h1, Wih + 1600 * 400, bsum + 1600, pre, 1600, 400, 1, 0);
  k_scan<<<4, 512, 0, stream>>>(Whh, pre, h2, hbuf1, 1);

  // head/dep stage 1 (dual), stage 2 (dual)
  k_gemm_bt_dual<<<dim3(7, 8, 2), 256, 0, stream>>>(h2, W_h1, b_h1, m1h,
                                                    h2, W_d1, b_d1, m1d, 400, 400, 1, 1);
  k_gemm_bt_dual<<<dim3(7, 8, 2), 256, 0, stream>>>(m1h, W_h2, b_h2, m2,
                                                    m1d, W_d2, b_d2, m3, 400, 400, 1, 1);

  // bilinear: t1[j][d] = sum_e dep[j][e] W_bi[d][e]; out[i][j] = head_i . t1_j + b
  k_gemm_bt<<<dim3(7, 8), 256, 0, stream>>>(m3, W_bi, nullptr, t1, 400, 400, 0, 0);
  k_gemm_bt<<<dim3(8, 8), 256, 0, stream>>>(m2, t1, b_bi, out, 512, 400, 2, 0);
}

// Round 5
// 1611.636 us; speedup vs baseline: 7.4226x; 1.5781x over previous
//
#include <hip/hip_runtime.h>
#include <hip/hip_bf16.h>
#include <cstdint>
#include <cstddef>

// BiLSTM tagger, f32 end-to-end.
// embed -> [GEMM pre -> 8-block LSTM scan] x2 -> MLP GEMMs (dual) -> bilinear.
// Scan: 8 working blocks (2 dirs x 4 parts), 448 thr. Each block: 200 gate rows,
// each row split across 2 threads (u = tid&1) -> 25 float4 = 100 weight VGPRs/thread,
// UNDER the observed 128-VGPR allocator budget (r3/r4: 200-VGPR arrays spill at any
// launch_bounds). Cross-block h exchange: packed (tag<<32|value) u64 words in L2,
// double-buffered by parity; reader spins on the data word itself. Blocks mapped to
// bids {0,8,16,24} (dir0) / {1,9,17,25} (dir1) so partners share an XCD if bid%8
// round-robins XCDs (perf-only assumption).

#define TSEQ 512
#define HDIR 200
#define INSZ 400
#define G4   800

typedef unsigned long long u64;

// ---------------- embedding ----------------
__global__ void k_embed(const float* __restrict__ we, const float* __restrict__ pe,
                        const int* __restrict__ wi, const int* __restrict__ pi,
                        float* __restrict__ x) {
  int t = blockIdx.x;
  int w = wi[t], p = pi[t];
  const float* wrow = we + (size_t)w * 300;
  const float* prow = pe + (size_t)p * 100;
  for (int j = threadIdx.x; j < INSZ; j += blockDim.x)
    x[(size_t)t * INSZ + j] = (j < 300) ? wrow[j] : prow[j - 300];
}

__global__ void k_add(const float* __restrict__ a, const float* __restrict__ b,
                      float* __restrict__ o, int n) {
  int i = blockIdx.x * blockDim.x + threadIdx.x;
  if (i < n) o[i] = a[i] + b[i];
}

// ---------------- GEMM: C[n][m] = act(A[n][k] * B[m][k]^T + bias) ----------------
__device__ __forceinline__ void gemm_bt_body(
    const float* __restrict__ A, const float* __restrict__ B,
    const float* __restrict__ bias, float* __restrict__ C,
    int m, int k, int bias_mode, int do_relu, int bx, int by)
{
  __shared__ float As[16][68];
  __shared__ float Bs[16][68];
  const int tid = threadIdx.x;
  const int tx = tid & 15, ty = tid >> 4;
  const int row0 = by << 6, col0 = bx << 6;
  const int lr = tid >> 2;
  const int kq = (tid & 3) << 2;
  float acc[4][4] = {};

  for (int ks = 0; ks < k; ks += 16) {
    float4 a4 = *(const float4*)(A + (size_t)(row0 + lr) * k + ks + kq);
    float4 b4 = make_float4(0.f, 0.f, 0.f, 0.f);
    if (col0 + lr < m)
      b4 = *(const float4*)(B + (size_t)(col0 + lr) * k + ks + kq);
    As[kq + 0][lr] = a4.x; As[kq + 1][lr] = a4.y; As[kq + 2][lr] = a4.z; As[kq + 3][lr] = a4.w;
    Bs[kq + 0][lr] = b4.x; Bs[kq + 1][lr] = b4.y; Bs[kq + 2][lr] = b4.z; Bs[kq + 3][lr] = b4.w;
    __syncthreads();
#pragma unroll
    for (int kk = 0; kk < 16; ++kk) {
      const float4 av = *(const float4*)&As[kk][ty << 2];
      const float4 bv = *(const float4*)&Bs[kk][tx << 2];
      const float a_[4] = {av.x, av.y, av.z, av.w};
      const float b_[4] = {bv.x, bv.y, bv.z, bv.w};
#pragma unroll
      for (int i = 0; i < 4; ++i)
#pragma unroll
        for (int j = 0; j < 4; ++j)
          acc[i][j] += a_[i] * b_[j];
    }
    __syncthreads();
  }

#pragma unroll
  for (int i = 0; i < 4; ++i) {
    const int r = row0 + (ty << 2) + i;
#pragma unroll
    for (int j = 0; j < 4; ++j) {
      const int c = col0 + (tx << 2) + j;
      if (c < m) {
        float v = acc[i][j];
        if (bias_mode == 1) v += bias[c];
        else if (bias_mode == 2) v += bias[0];
        if (do_relu) v = fmaxf(v, 0.f);
        C[(size_t)r * m + c] = v;
      }
    }
  }
}

__global__ __launch_bounds__(256) void k_gemm_bt(
    const float* __restrict__ A, const float* __restrict__ B,
    const float* __restrict__ bias, float* __restrict__ C,
    int m, int k, int bias_mode, int do_relu)
{
  gemm_bt_body(A, B, bias, C, m, k, bias_mode, do_relu, blockIdx.x, blockIdx.y);
}

__global__ __launch_bounds__(256) void k_gemm_bt_dual(
    const float* __restrict__ A0, const float* __restrict__ B0,
    const float* __restrict__ bias0, float* __restrict__ C0,
    const float* __restrict__ A1, const float* __restrict__ B1,
    const float* __restrict__ bias1, float* __restrict__ C1,
    int m, int k, int bias_mode, int do_relu)
{
  const float* A = blockIdx.z ? A1 : A0;
  const float* B = blockIdx.z ? B1 : B0;
  const float* bias = blockIdx.z ? bias1 : bias0;
  float* C = blockIdx.z ? C1 : C0;
  gemm_bt_body(A, B, bias, C, m, k, bias_mode, do_relu, blockIdx.x, blockIdx.y);
}

// ---------------- LSTM scan ----------------
// Working blocks: dir = bid&7 (0/1), part p = bid>>3 (0..3); others exit.
// Thread (rr = tid>>1, u = tid&1), rr<200: gate g = rr/50, q = rr%50,
// grow = g*200 + p*50 + q; columns [u*100, u*100+100) -> 25 float4 VGPRs.
// Block owns h slice [p*50, (p+1)*50). hbuf: u64[2 slot][2 dir][200].
__global__ __launch_bounds__(448, 1) void k_scan(
    const float* __restrict__ Whh,   // [2][2][800][200]
    const float* __restrict__ pre,   // [512][1600]
    float* __restrict__ hs,          // [512][400] (concat fwd|bwd)
    u64* hbuf,                       // zeroed by host each launch
    int layer)
{
  const int bid = blockIdx.x;
  if ((bid & 7) > 1) return;
  const int dir = bid & 7;
  const int p = bid >> 3;
  const int tid = threadIdx.x;
  const int rr = tid >> 1;
  const int u = tid & 1;
  const bool act = rr < HDIR;
  const int g = rr / 50;
  const int q = rr - g * 50;
  const int grow = act ? (g * HDIR + p * 50 + q) : 0;
  const int own0 = p * 50;

  __shared__ float h_lds[HDIR];
  __shared__ float g_lds[HDIR];      // activated gate values [g*50+q]

  float4 w[25];                      // compile-time indices only
  {
    const float* wrow = Whh + ((size_t)(layer * 2 + dir) * G4 + grow) * HDIR + u * 100;
#pragma unroll
    for (int i = 0; i < 25; ++i) w[i] = *(const float4*)(wrow + i * 4);
  }

  for (int i = tid; i < HDIR; i += 448) h_lds[i] = 0.f;
  float c_state = 0.f;               // valid for tid < 50
  u64* hb_dir = hbuf + dir * HDIR;   // + slot*400
  __syncthreads();

  for (int t = 0; t < TSEQ; ++t) {
    const int inrow = dir ? (TSEQ - 1 - t) : t;

    float preval = 0.f;
    if (act && u == 0)
      preval = pre[(size_t)inrow * 1600 + dir * G4 + grow];

    // gather 3 remote 50-slices (packed words; tag carries the data)
    if (t > 0 && tid < 150) {
      const int j = (tid < own0) ? tid : tid + 50;
      const u64* src = hb_dir + (size_t)(t & 1) * 400 + j;
      u64 v;
      do {
        v = __hip_atomic_load(src, __ATOMIC_RELAXED, __HIP_MEMORY_SCOPE_AGENT);
      } while ((unsigned)(v >> 32) < (unsigned)t);
      union { unsigned uu; float f; } cv; cv.uu = (unsigned)v;
      h_lds[j] = cv.f;
    }
    __syncthreads();   // B1: h_lds complete (own written end of prev iter)

    if (act) {
      float4 acc = make_float4(0.f, 0.f, 0.f, 0.f);
      const float* hb = h_lds + u * 100;
#pragma unroll
      for (int i = 0; i < 25; ++i) {
        const float4 hv = *(const float4*)(hb + i * 4);
        acc.x += w[i].x * hv.x; acc.y += w[i].y * hv.y;
        acc.z += w[i].z * hv.z; acc.w += w[i].w * hv.w;
      }
      float tot = acc.x + acc.y + acc.z + acc.w;
      tot += __shfl_xor(tot, 1);     // combine column halves (adjacent lanes)
      if (u == 0) {
        const float gv = tot + preval;
        const float xx = (g == 2) ? 2.f * gv : gv;     // tanh = 2*sig(2x)-1
        const float s = 1.f / (1.f + __expf(-xx));
        g_lds[rr] = (g == 2) ? (2.f * s - 1.f) : s;
      }
    }
    __syncthreads();   // B2: g_lds ready

    if (tid < 50) {
      const float ai = g_lds[tid];
      const float af = g_lds[50 + tid];
      const float ag = g_lds[100 + tid];
      const float ao = g_lds[150 + tid];
      c_state = af * c_state + ai * ag;
      const float th = 2.f / (1.f + __expf(-2.f * c_state)) - 1.f;
      const float hv = ao * th;
      if (t != TSEQ - 1) {           // publish first: critical L2 word leaves early
        union { float f; unsigned uu; } cv; cv.f = hv;
        const u64 pk = ((u64)(unsigned)(t + 1) << 32) | cv.uu;
        __hip_atomic_store(hb_dir + (size_t)((t + 1) & 1) * 400 + own0 + tid,
                           pk, __ATOMIC_RELAXED, __HIP_MEMORY_SCOPE_AGENT);
      }
      h_lds[own0 + tid] = hv;
      hs[(size_t)inrow * INSZ + dir * HDIR + own0 + tid] = hv;
    }
    // no barrier here: B1 of next iter orders h_lds[own] for FMA readers;
    // spin writers touch disjoint h_lds slices after passing B2.
  }
}

// ---------------- host ----------------
extern "C" void kernel_launch(void* const* d_in, const int* in_sizes, int n_in,
                              void* d_out, int out_size, void* d_ws, size_t ws_size,
                              hipStream_t stream)
{
  const float* we   = (const float*)d_in[0];
  const float* pe   = (const float*)d_in[1];
  const float* Wih  = (const float*)d_in[2];
  const float* Whh  = (const float*)d_in[3];
  const float* bih  = (const float*)d_in[4];
  const float* bhh  = (const float*)d_in[5];
  const float* W_h1 = (const float*)d_in[6];
  const float* b_h1 = (const float*)d_in[7];
  const float* W_h2 = (const float*)d_in[8];
  const float* b_h2 = (const float*)d_in[9];
  const float* W_d1 = (const float*)d_in[10];
  const float* b_d1 = (const float*)d_in[11];
  const float* W_d2 = (const float*)d_in[12];
  const float* b_d2 = (const float*)d_in[13];
  const float* W_bi = (const float*)d_in[14];
  const float* b_bi = (const float*)d_in[15];
  const int*   wi   = (const int*)d_in[16];
  const int*   pi   = (const int*)d_in[17];
  float* out = (float*)d_out;

  float* ws = (float*)d_ws;
  float* x0   = ws;                     // 512*400
  float* pre  = ws + 204800;            // 512*1600
  float* h1   = ws + 1024000;           // 512*400
  float* h2   = ws + 1228800;           // 512*400
  float* m1h  = ws + 1433600;           // 512*400
  float* m1d  = ws + 1638400;           // 512*400
  float* m2   = ws + 1843200;           // 512*400 (head)
  float* m3   = ws + 2048000;           // 512*400 (dep)
  float* t1   = ws + 2252800;           // 512*400
  float* bsum = ws + 2457600;           // 3200
  u64* hbuf0  = (u64*)(ws + 2461696);   // 800 u64, layer 0
  u64* hbuf1  = hbuf0 + 800;            // layer 1

  hipMemsetAsync(hbuf0, 0, 2 * 800 * sizeof(u64), stream);
  k_embed<<<TSEQ, 128, 0, stream>>>(we, pe, wi, pi, x0);
  k_add<<<(3200 + 255) / 256, 256, 0, stream>>>(bih, bhh, bsum, 3200);

  // layer 0
  k_gemm_bt<<<dim3(25, 8), 256, 0, stream>>>(x0, Wih, bsum, pre, 1600, 400, 1, 0);
  k_scan<<<26, 448, 0, stream>>>(Whh, pre, h1, hbuf0, 0);
  // layer 1
  k_gemm_bt<<<dim3(25, 8), 256, 0, stream>>>(h1, Wih + 1600 * 400, bsum + 1600, pre, 1600, 400, 1, 0);
  k_scan<<<26, 448, 0, stream>>>(Whh, pre, h2, hbuf1, 1);

  // head/dep stage 1 (dual), stage 2 (dual)
  k_gemm_bt_dual<<<dim3(7, 8, 2), 256, 0, stream>>>(h2, W_h1, b_h1, m1h,
                                                    h2, W_d1, b_d1, m1d, 400, 400, 1, 1);
  k_gemm_bt_dual<<<dim3(7, 8, 2), 256, 0, stream>>>(m1h, W_h2, b_h2, m2,
                                                    m1d, W_d2, b_d2, m3, 400, 400, 1, 1);

  // bilinear: t1[j][d] = sum_e dep[j][e] W_bi[d][e]; out[i][j] = head_i . t1_j + b
  k_gemm_bt<<<dim3(7, 8), 256, 0, stream>>>(m3, W_bi, nullptr, t1, 400, 400, 0, 0);
  k_gemm_bt<<<dim3(8, 8), 256, 0, stream>>>(m2, t1, b_bi, out, 512, 400, 2, 0);
}